// Round 1
// baseline (772.290 us; speedup 1.0000x reference)
//
#include <hip/hip_runtime.h>
#include <math.h>

constexpr int S   = 64;
constexpr int B   = 32;
constexpr int HID = 16;
constexpr int EMB = 32;
constexpr int V   = 50257;
constexpr int CH  = 2*HID;      // 32 = concat width = K of the big GEMM
constexpr int IN  = EMB + HID;  // 48
constexpr int VPB = 512;        // v-columns per block (2 per thread)
constexpr int RPB = 64;         // rows per block

// ---- K1: embedding gather + input contribution of all 4 gates ------------
// xw[sb][g*16+h] = b_g[h] + sum_k emb[tok[sb]][k] * W_g[h][k]   (k < 32)
__global__ __launch_bounds__(64) void k1_xw(
    const int* __restrict__ tok, const float* __restrict__ embT,
    const float* __restrict__ Wf, const float* __restrict__ bf,
    const float* __restrict__ Wi, const float* __restrict__ bi,
    const float* __restrict__ Wc, const float* __restrict__ bc,
    const float* __restrict__ Wo, const float* __restrict__ bo,
    float* __restrict__ xw)
{
    int sb = blockIdx.x, t = threadIdx.x;
    __shared__ float e[EMB];
    if (t < EMB) e[t] = embT[(long)tok[sb]*EMB + t];
    __syncthreads();
    int g = t >> 4, h = t & 15;
    const float* W  = (g==0) ? Wf : (g==1) ? Wi : (g==2) ? Wc : Wo;
    const float* bv = (g==0) ? bf : (g==1) ? bi : (g==2) ? bc : bo;
    const float* wr = W + h*IN;
    float acc = bv[h];
    #pragma unroll
    for (int k = 0; k < EMB; ++k) acc += e[k]*wr[k];
    xw[sb*64 + t] = acc;
}

// ---- K2: the two LSTM scans (blockIdx.x = direction) ---------------------
// Writes pre-update state into concat[t][b][dir*16 + h]:
//   fwd: lefts[t]  = state after tokens 0..t-1
//   bwd: rights[t] = state after tokens S-1..t+1
__global__ __launch_bounds__(512) void k2_scan(
    const float* __restrict__ xw,
    const float* __restrict__ Wf, const float* __restrict__ Wi,
    const float* __restrict__ Wc, const float* __restrict__ Wo,
    const float* __restrict__ h0, const float* __restrict__ C0,
    float* __restrict__ hcat)
{
    int dir = blockIdx.x;
    int t = threadIdx.x, b = t >> 4, hh = t & 15;
    __shared__ float U[4][HID][HID+1];   // +1 pad: break 16-stride bank aliasing
    __shared__ float hbuf[B][HID];
    for (int i = t; i < 4*HID*HID; i += 512) {
        int g = i >> 8, rem = i & 255, h = rem >> 4, k = rem & 15;
        const float* W = (g==0) ? Wf : (g==1) ? Wi : (g==2) ? Wc : Wo;
        U[g][h][k] = W[h*IN + EMB + k];
    }
    float h_own = h0[hh];
    float C     = C0[hh];
    hbuf[b][hh] = h_own;
    __syncthreads();
    for (int step = 0; step < S; ++step) {
        int s  = dir ? (S-1-step) : step;
        int sb = s*B + b;
        hcat[sb*CH + dir*HID + hh] = h_own;   // state BEFORE consuming token s
        const float* x = xw + sb*64;
        float pf = x[hh], pi = x[16+hh], pc = x[32+hh], po = x[48+hh];
        #pragma unroll
        for (int k = 0; k < HID; ++k) {
            float hv = hbuf[b][k];
            pf += U[0][hh][k]*hv;
            pi += U[1][hh][k]*hv;
            pc += U[2][hh][k]*hv;
            po += U[3][hh][k]*hv;
        }
        float fg = 1.f/(1.f + __expf(-pf));
        float ig = 1.f/(1.f + __expf(-pi));
        float cg = tanhf(pc);
        float og = 1.f/(1.f + __expf(-po));
        C     = fg*C + ig*cg;
        h_own = og*tanhf(C);
        __syncthreads();           // everyone done reading old hbuf
        hbuf[b][hh] = h_own;
        __syncthreads();           // new hbuf visible
    }
}

// ---- K3: pass A — per-row sum of exp(logit), no max shift needed ---------
// |logit| <= 32*0.25*1 + 0.25 = 8.25  =>  fp32 sum-exp is safe & accurate.
__global__ __launch_bounds__(256) void k3_sums(
    const float* __restrict__ hcat, const float* __restrict__ Who,
    const float* __restrict__ bho, float* __restrict__ row_sums)
{
    int t  = threadIdx.x;
    int v0 = blockIdx.x*VPB + t, v1 = v0 + 256;
    int r0 = blockIdx.y*RPB;
    bool ok0 = v0 < V, ok1 = v1 < V;
    float w0[CH], w1[CH];
    float b0 = ok0 ? bho[v0] : 0.f;
    float b1 = ok1 ? bho[v1] : 0.f;
    #pragma unroll
    for (int k = 0; k < CH; k += 4) {
        float4 f0 = ok0 ? *(const float4*)(Who + (long)v0*CH + k) : make_float4(0.f,0.f,0.f,0.f);
        float4 f1 = ok1 ? *(const float4*)(Who + (long)v1*CH + k) : make_float4(0.f,0.f,0.f,0.f);
        w0[k]=f0.x; w0[k+1]=f0.y; w0[k+2]=f0.z; w0[k+3]=f0.w;
        w1[k]=f1.x; w1[k+1]=f1.y; w1[k+2]=f1.z; w1[k+3]=f1.w;
    }
    __shared__ float partial[4][RPB];
    int wave = t >> 6, lane = t & 63;
    for (int r = 0; r < RPB; ++r) {
        const float* hr = hcat + (r0 + r)*CH;   // block-uniform -> s_loads
        float a0 = b0, a1 = b1;
        #pragma unroll
        for (int k = 0; k < CH; ++k) { float hv = hr[k]; a0 += hv*w0[k]; a1 += hv*w1[k]; }
        float e = (ok0 ? __expf(a0) : 0.f) + (ok1 ? __expf(a1) : 0.f);
        #pragma unroll
        for (int off = 32; off; off >>= 1) e += __shfl_xor(e, off);
        if (lane == 0) partial[wave][r] = e;
    }
    __syncthreads();
    if (t < RPB) {
        float s4 = partial[0][t] + partial[1][t] + partial[2][t] + partial[3][t];
        atomicAdd(&row_sums[r0 + t], s4);
    }
}

__global__ __launch_bounds__(256) void k3b_log(
    const float* __restrict__ sums, float* __restrict__ logz)
{
    int i = blockIdx.x*256 + threadIdx.x;
    if (i < S*B) logz[i] = logf(sums[i]);
}

// ---- K4: pass B — recompute logits, write logit - logZ -------------------
__global__ __launch_bounds__(256) void k4_out(
    const float* __restrict__ hcat, const float* __restrict__ Who,
    const float* __restrict__ bho, const float* __restrict__ logz,
    float* __restrict__ out)
{
    int t  = threadIdx.x;
    int v0 = blockIdx.x*VPB + t, v1 = v0 + 256;
    int r0 = blockIdx.y*RPB;
    bool ok0 = v0 < V, ok1 = v1 < V;
    float w0[CH], w1[CH];
    float b0 = ok0 ? bho[v0] : 0.f;
    float b1 = ok1 ? bho[v1] : 0.f;
    #pragma unroll
    for (int k = 0; k < CH; k += 4) {
        float4 f0 = ok0 ? *(const float4*)(Who + (long)v0*CH + k) : make_float4(0.f,0.f,0.f,0.f);
        float4 f1 = ok1 ? *(const float4*)(Who + (long)v1*CH + k) : make_float4(0.f,0.f,0.f,0.f);
        w0[k]=f0.x; w0[k+1]=f0.y; w0[k+2]=f0.z; w0[k+3]=f0.w;
        w1[k]=f1.x; w1[k+1]=f1.y; w1[k+2]=f1.z; w1[k+3]=f1.w;
    }
    __shared__ float lz[RPB];
    if (t < RPB) lz[t] = logz[r0 + t];
    __syncthreads();
    for (int r = 0; r < RPB; ++r) {
        const float* hr = hcat + (r0 + r)*CH;   // block-uniform -> s_loads
        float a0 = b0, a1 = b1;
        #pragma unroll
        for (int k = 0; k < CH; ++k) { float hv = hr[k]; a0 += hv*w0[k]; a1 += hv*w1[k]; }
        float l = lz[r];
        long base = (long)(r0 + r)*V;
        if (ok0) out[base + v0] = a0 - l;   // consecutive lanes -> coalesced
        if (ok1) out[base + v1] = a1 - l;
    }
}

extern "C" void kernel_launch(void* const* d_in, const int* in_sizes, int n_in,
                              void* d_out, int out_size, void* d_ws, size_t ws_size,
                              hipStream_t stream)
{
    const int*   tok = (const int*)d_in[0];
    const float* emb = (const float*)d_in[1];
    const float* Wf  = (const float*)d_in[2];
    const float* bf  = (const float*)d_in[3];
    const float* Wi  = (const float*)d_in[4];
    const float* bi  = (const float*)d_in[5];
    const float* Wc  = (const float*)d_in[6];
    const float* bc  = (const float*)d_in[7];
    const float* Wo  = (const float*)d_in[8];
    const float* bo  = (const float*)d_in[9];
    const float* Who = (const float*)d_in[10];
    const float* bho = (const float*)d_in[11];
    const float* h0  = (const float*)d_in[12];
    const float* C0  = (const float*)d_in[13];
    float* out = (float*)d_out;

    // workspace layout (floats): xw | hcat | row_sums | logz   (~800 KB total)
    float* xw       = (float*)d_ws;          // S*B*64
    float* hcat     = xw + S*B*64;           // S*B*CH
    float* row_sums = hcat + S*B*CH;         // S*B
    float* logz     = row_sums + S*B;        // S*B

    hipMemsetAsync(row_sums, 0, S*B*sizeof(float), stream);
    k1_xw<<<dim3(S*B), dim3(64), 0, stream>>>(tok, emb, Wf, bf, Wi, bi, Wc, bc, Wo, bo, xw);
    k2_scan<<<dim3(2), dim3(512), 0, stream>>>(xw, Wf, Wi, Wc, Wo, h0, C0, hcat);
    dim3 g3((V + VPB - 1)/VPB, (S*B)/RPB);   // (99, 32)
    k3_sums<<<g3, dim3(256), 0, stream>>>(hcat, Who, bho, row_sums);
    k3b_log<<<dim3((S*B + 255)/256), dim3(256), 0, stream>>>(row_sums, logz);
    k4_out<<<g3, dim3(256), 0, stream>>>(hcat, Who, bho, logz, out);
}

// Round 2
// 625.045 us; speedup vs baseline: 1.2356x; 1.2356x over previous
//
#include <hip/hip_runtime.h>
#include <hip/hip_bf16.h>
#include <math.h>

constexpr int S   = 64;
constexpr int B   = 32;
constexpr int HID = 16;
constexpr int EMB = 32;
constexpr int V   = 50257;
constexpr int CH  = 2*HID;       // 32 = K of the big GEMM (one MFMA K exactly)
constexpr int IN  = EMB + HID;   // 48
constexpr int VPAD = 50272;      // 3142 * 16
constexpr int NT   = VPAD/16;    // 3142 n-tiles
constexpr int MT   = (S*B)/16;   // 128 m-tiles
constexpr int NSTRIP = 16;
constexpr int NT_PER = (NT + NSTRIP - 1)/NSTRIP;  // 197

typedef __attribute__((ext_vector_type(8))) short bf16x8;  // 8 bf16 = 4 VGPRs
typedef __attribute__((ext_vector_type(4))) float f32x4;

__device__ inline float sigm(float x)      { return 1.f/(1.f + __expf(-x)); }
__device__ inline float tanh_fast(float x) { return 1.f - 2.f/(1.f + __expf(2.f*x)); }

// ---- K0: convert W_ho -> bf16 (padded, zero rows >= V), b_ho -> fp32 padded (-30)
__global__ __launch_bounds__(256) void k0_conv(
    const float* __restrict__ Who, const float* __restrict__ bho,
    __hip_bfloat16* __restrict__ WhoB, float* __restrict__ bhoP)
{
    int i = blockIdx.x*256 + threadIdx.x;
    if (i < VPAD*CH) {
        int r = i >> 5;
        WhoB[i] = __float2bfloat16((r < V) ? Who[i] : 0.f);
    }
    if (i < VPAD) bhoP[i] = (i < V) ? bho[i] : -30.f;
}

// ---- K1: embedding gather + input contribution of all 4 gates ------------
__global__ __launch_bounds__(64) void k1_xw(
    const int* __restrict__ tok, const float* __restrict__ embT,
    const float* __restrict__ Wf, const float* __restrict__ bf,
    const float* __restrict__ Wi, const float* __restrict__ bi,
    const float* __restrict__ Wc, const float* __restrict__ bc,
    const float* __restrict__ Wo, const float* __restrict__ bo,
    float* __restrict__ xw)
{
    int sb = blockIdx.x, t = threadIdx.x;
    __shared__ float e[EMB];
    if (t < EMB) e[t] = embT[(long)tok[sb]*EMB + t];
    __syncthreads();
    int g = t >> 4, h = t & 15;
    const float* W  = (g==0) ? Wf : (g==1) ? Wi : (g==2) ? Wc : Wo;
    const float* bv = (g==0) ? bf : (g==1) ? bi : (g==2) ? bc : bo;
    const float* wr = W + h*IN;
    float acc = bv[h];
    #pragma unroll
    for (int k = 0; k < EMB; ++k) acc += e[k]*wr[k];
    xw[sb*64 + t] = acc;   // layout [sb][g*16+h] matches k2's lane order
}

// ---- K2: 64 independent scans (dir,batch), one wave each, no barriers ----
// lane = g*16 + hh. All lanes redundantly maintain (h, C) for their hh.
// hcat written as bf16, "state BEFORE consuming token s".
__global__ __launch_bounds__(64) void k2_scan(
    const float* __restrict__ xw,
    const float* __restrict__ Wf, const float* __restrict__ Wi,
    const float* __restrict__ Wc, const float* __restrict__ Wo,
    const float* __restrict__ h0, const float* __restrict__ C0,
    __hip_bfloat16* __restrict__ hcatB)
{
    int id  = blockIdx.x;           // 0..63
    int dir = id >> 5, b = id & 31;
    int lane = threadIdx.x;
    int g = lane >> 4, hh = lane & 15;
    const float* W = (g==0) ? Wf : (g==1) ? Wi : (g==2) ? Wc : Wo;
    float U[HID];
    #pragma unroll
    for (int k = 0; k < HID; ++k) U[k] = W[hh*IN + EMB + k];
    float h = h0[hh], C = C0[hh];
    for (int step = 0; step < S; ++step) {
        int s  = dir ? (S-1-step) : step;
        int sb = s*B + b;
        if (g == 0) hcatB[sb*CH + dir*HID + hh] = __float2bfloat16(h);
        float p = xw[sb*64 + lane];
        #pragma unroll
        for (int k = 0; k < HID; ++k) p += U[k]*__shfl(h, k, 64); // h from lane k (g=0)
        float a = (g==2) ? tanh_fast(p) : sigm(p);
        float fg = __shfl(a,      hh, 64);
        float ig = __shfl(a, 16 + hh, 64);
        float cg = __shfl(a, 32 + hh, 64);
        float og = __shfl(a, 48 + hh, 64);
        C = fg*C + ig*cg;
        h = og*tanh_fast(C);
    }
}

// ---- KA: pass A — MFMA logits, accumulate sum(exp) per row ----------------
// D layout: col = lane&15 (v), row = quad*4+reg (m). |logit|<=8.25 -> no max shift.
__global__ __launch_bounds__(256) void kA(
    const __hip_bfloat16* __restrict__ hcatB, const __hip_bfloat16* __restrict__ WhoB,
    const float* __restrict__ bhoP, float* __restrict__ row_sums)
{
    int t = threadIdx.x, w = t >> 6, lane = t & 63;
    int col = lane & 15, quad = lane >> 4;
    int r0 = (blockIdx.y*4 + w)*16;
    int n0 = blockIdx.x*NT_PER;
    int n1 = (n0 + NT_PER < NT) ? n0 + NT_PER : NT;
    bf16x8 a = *(const bf16x8*)((const short*)hcatB + (r0+col)*CH + quad*8);
    float acc0=0.f, acc1=0.f, acc2=0.f, acc3=0.f;
    for (int nt = n0; nt < n1; ++nt) {
        int v0 = nt*16;
        bf16x8 bfr = *(const bf16x8*)((const short*)WhoB + (long)(v0+col)*CH + quad*8);
        float bv = bhoP[v0+col];
        f32x4 d = {0.f,0.f,0.f,0.f};
        d = __builtin_amdgcn_mfma_f32_16x16x32_bf16(a, bfr, d, 0, 0, 0);
        acc0 += __expf(d[0]+bv);
        acc1 += __expf(d[1]+bv);
        acc2 += __expf(d[2]+bv);
        acc3 += __expf(d[3]+bv);
    }
    #pragma unroll
    for (int off = 1; off < 16; off <<= 1) {   // reduce across the 16 lanes of a quad
        acc0 += __shfl_xor(acc0, off);
        acc1 += __shfl_xor(acc1, off);
        acc2 += __shfl_xor(acc2, off);
        acc3 += __shfl_xor(acc3, off);
    }
    if (col == 0) {
        atomicAdd(&row_sums[r0 + quad*4 + 0], acc0);
        atomicAdd(&row_sums[r0 + quad*4 + 1], acc1);
        atomicAdd(&row_sums[r0 + quad*4 + 2], acc2);
        atomicAdd(&row_sums[r0 + quad*4 + 3], acc3);
    }
}

__global__ __launch_bounds__(256) void k3b_log(
    const float* __restrict__ sums, float* __restrict__ logz)
{
    int i = blockIdx.x*256 + threadIdx.x;
    if (i < S*B) logz[i] = logf(sums[i]);
}

// ---- KB: pass B — recompute logits via MFMA, write logit - logZ ----------
__global__ __launch_bounds__(256) void kB(
    const __hip_bfloat16* __restrict__ hcatB, const __hip_bfloat16* __restrict__ WhoB,
    const float* __restrict__ bhoP, const float* __restrict__ logz,
    float* __restrict__ out)
{
    int t = threadIdx.x, w = t >> 6, lane = t & 63;
    int col = lane & 15, quad = lane >> 4;
    int r0 = (blockIdx.y*4 + w)*16;
    int n0 = blockIdx.x*NT_PER;
    int n1 = (n0 + NT_PER < NT) ? n0 + NT_PER : NT;
    bf16x8 a = *(const bf16x8*)((const short*)hcatB + (r0+col)*CH + quad*8);
    float lz0 = logz[r0 + quad*4 + 0];
    float lz1 = logz[r0 + quad*4 + 1];
    float lz2 = logz[r0 + quad*4 + 2];
    float lz3 = logz[r0 + quad*4 + 3];
    float* prow = out + (long)(r0 + quad*4)*V + col;
    for (int nt = n0; nt < n1; ++nt) {
        int v0 = nt*16;
        bf16x8 bfr = *(const bf16x8*)((const short*)WhoB + (long)(v0+col)*CH + quad*8);
        float bv = bhoP[v0+col];
        f32x4 d = {0.f,0.f,0.f,0.f};
        d = __builtin_amdgcn_mfma_f32_16x16x32_bf16(a, bfr, d, 0, 0, 0);
        if (v0 + col < V) {
            prow[0L*V + v0] = d[0] + bv - lz0;
            prow[1L*V + v0] = d[1] + bv - lz1;
            prow[2L*V + v0] = d[2] + bv - lz2;
            prow[3L*V + v0] = d[3] + bv - lz3;
        }
    }
}

extern "C" void kernel_launch(void* const* d_in, const int* in_sizes, int n_in,
                              void* d_out, int out_size, void* d_ws, size_t ws_size,
                              hipStream_t stream)
{
    const int*   tok = (const int*)d_in[0];
    const float* emb = (const float*)d_in[1];
    const float* Wf  = (const float*)d_in[2];
    const float* bf  = (const float*)d_in[3];
    const float* Wi  = (const float*)d_in[4];
    const float* bi  = (const float*)d_in[5];
    const float* Wc  = (const float*)d_in[6];
    const float* bc  = (const float*)d_in[7];
    const float* Wo  = (const float*)d_in[8];
    const float* bo  = (const float*)d_in[9];
    const float* Who = (const float*)d_in[10];
    const float* bho = (const float*)d_in[11];
    const float* h0  = (const float*)d_in[12];
    const float* C0  = (const float*)d_in[13];
    float* out = (float*)d_out;

    // workspace layout (all 16B-aligned sizes)
    char* p = (char*)d_ws;
    __hip_bfloat16* WhoB  = (__hip_bfloat16*)p; p += (size_t)VPAD*CH*2;  // 3.2 MB
    __hip_bfloat16* hcatB = (__hip_bfloat16*)p; p += (size_t)S*B*CH*2;   // 128 KB
    float* bhoP     = (float*)p; p += (size_t)VPAD*4;                     // 200 KB
    float* xw       = (float*)p; p += (size_t)S*B*64*4;                   // 512 KB
    float* row_sums = (float*)p; p += (size_t)S*B*4;
    float* logz     = (float*)p;

    hipMemsetAsync(row_sums, 0, S*B*sizeof(float), stream);
    k0_conv<<<dim3((VPAD*CH + 255)/256), dim3(256), 0, stream>>>(Who, bho, WhoB, bhoP);
    k1_xw<<<dim3(S*B), dim3(64), 0, stream>>>(tok, emb, Wf, bf, Wi, bi, Wc, bc, Wo, bo, xw);
    k2_scan<<<dim3(64), dim3(64), 0, stream>>>(xw, Wf, Wi, Wc, Wo, h0, C0, hcatB);
    dim3 g(NSTRIP, MT/4);   // (16, 32)
    kA<<<g, dim3(256), 0, stream>>>(hcatB, WhoB, bhoP, row_sums);
    k3b_log<<<dim3((S*B + 255)/256), dim3(256), 0, stream>>>(row_sums, logz);
    kB<<<g, dim3(256), 0, stream>>>(hcatB, WhoB, bhoP, logz, out);
}

// Round 3
// 620.015 us; speedup vs baseline: 1.2456x; 1.0081x over previous
//
#include <hip/hip_runtime.h>
#include <hip/hip_bf16.h>
#include <math.h>

constexpr int S   = 64;
constexpr int B   = 32;
constexpr int HID = 16;
constexpr int EMB = 32;
constexpr int V   = 50257;
constexpr int CH  = 2*HID;        // 32 = K (exactly two 32x32x16 MFMAs)
constexpr int IN  = EMB + HID;    // 48
constexpr int VPAD = 50272;       // 1571 * 32
constexpr int NT32 = VPAD/32;     // 1571 n-tiles
constexpr int MT32 = (S*B)/32;    // 64 m-tiles
constexpr int NSTRIP = 32;
constexpr int NT_PER = (NT32 + NSTRIP - 1)/NSTRIP;   // 50
constexpr int NB_CONV = (VPAD*CH)/256;               // 6284 (exact)
constexpr int NB_XW   = (S*B)/4;                     // 512

typedef __attribute__((ext_vector_type(8)))  short bf16x8;   // 8 bf16 = 4 VGPRs
typedef __attribute__((ext_vector_type(16))) float f32x16;   // 32x32 accum

__device__ inline float sigm(float x)      { return 1.f/(1.f + __expf(-x)); }
__device__ inline float tanh_fast(float x) { return 1.f - 2.f/(1.f + __expf(2.f*x)); }

// ---- prep: W_ho->bf16 (pad rows>=V with 0), b_ho->fp32 (pad -30),
//            row_sums zero, and xw = emb-part of all 4 gates ---------------
__global__ __launch_bounds__(256) void kprep(
    const int* __restrict__ tok, const float* __restrict__ emb,
    const float* __restrict__ Wf, const float* __restrict__ bf,
    const float* __restrict__ Wi, const float* __restrict__ bi,
    const float* __restrict__ Wc, const float* __restrict__ bc,
    const float* __restrict__ Wo, const float* __restrict__ bo,
    const float* __restrict__ Who, const float* __restrict__ bho,
    __hip_bfloat16* __restrict__ WhoB, float* __restrict__ bhoP,
    float* __restrict__ xw, float* __restrict__ row_sums)
{
    int bid = blockIdx.x, t = threadIdx.x;
    if (bid < NB_CONV) {
        int i = bid*256 + t;                       // < VPAD*CH exactly
        int r = i >> 5;
        WhoB[i] = __float2bfloat16((r < V) ? Who[i] : 0.f);
        if (i < VPAD) bhoP[i] = (i < V) ? bho[i] : -30.f;
        if (i < S*B)  row_sums[i] = 0.f;
    } else {
        int grp = t >> 6, lane = t & 63;
        int sb  = (bid - NB_CONV)*4 + grp;
        __shared__ float e[4][EMB];
        if (lane < EMB) e[grp][lane] = emb[(long)tok[sb]*EMB + lane];
        __syncthreads();
        int g = lane >> 4, h = lane & 15;
        const float* W  = (g==0) ? Wf : (g==1) ? Wi : (g==2) ? Wc : Wo;
        const float* bv = (g==0) ? bf : (g==1) ? bi : (g==2) ? bc : bo;
        const float* wr = W + h*IN;
        float acc = bv[h];
        #pragma unroll
        for (int k = 0; k < EMB; ++k) acc += e[grp][k]*wr[k];
        xw[sb*64 + lane] = acc;
    }
}

// ---- k2: 64 independent scans (dir,batch), one wave each, xw prefetch ----
__global__ __launch_bounds__(64) void k2_scan(
    const float* __restrict__ xw,
    const float* __restrict__ Wf, const float* __restrict__ Wi,
    const float* __restrict__ Wc, const float* __restrict__ Wo,
    const float* __restrict__ h0, const float* __restrict__ C0,
    __hip_bfloat16* __restrict__ hcatB)
{
    int id  = blockIdx.x;            // 0..63
    int dir = id >> 5, b = id & 31;
    int lane = threadIdx.x;
    int g = lane >> 4, hh = lane & 15;
    const float* W = (g==0) ? Wf : (g==1) ? Wi : (g==2) ? Wc : Wo;
    float U[HID];
    #pragma unroll
    for (int k = 0; k < HID; ++k) U[k] = W[hh*IN + EMB + k];
    float h = h0[hh], C = C0[hh];
    int sb     = dir ? (S-1)*B + b : b;
    int stride = dir ? -B : B;
    float xn = xw[sb*64 + lane];
    for (int step = 0; step < S; ++step) {
        float p = xn;
        if (step + 1 < S) xn = xw[(sb + stride)*64 + lane];   // prefetch
        if (g == 0) hcatB[sb*CH + dir*HID + hh] = __float2bfloat16(h);
        float q0 = 0.f, q1 = 0.f, q2 = 0.f, q3 = 0.f;
        #pragma unroll
        for (int k = 0; k < HID; k += 4) {            // 4 independent chains
            q0 += U[k  ]*__shfl(h, k,   64);
            q1 += U[k+1]*__shfl(h, k+1, 64);
            q2 += U[k+2]*__shfl(h, k+2, 64);
            q3 += U[k+3]*__shfl(h, k+3, 64);
        }
        p += (q0+q1) + (q2+q3);
        float a = (g==2) ? tanh_fast(p) : sigm(p);
        float fg = __shfl(a,      hh, 64);
        float ig = __shfl(a, 16 + hh, 64);
        float cg = __shfl(a, 32 + hh, 64);
        float og = __shfl(a, 48 + hh, 64);
        C = fg*C + ig*cg;
        h = og*tanh_fast(C);
        sb += stride;
    }
}

// ---- kA: sum exp(logit) per row. 32x32 MFMA, bias seeded in accum. -------
// |logit| <= 8.25 -> fp32 sum-exp safe, no max shift.
__global__ __launch_bounds__(256) void kA(
    const __hip_bfloat16* __restrict__ hcatB, const __hip_bfloat16* __restrict__ WhoB,
    const float* __restrict__ bhoP, float* __restrict__ row_sums)
{
    int t = threadIdx.x, w = t >> 6, lane = t & 63;
    int l31 = lane & 31, half = lane >> 5;
    int r0 = (blockIdx.y*4 + w)*32;
    int n0 = blockIdx.x*NT_PER;
    int n1 = (n0 + NT_PER < NT32) ? n0 + NT_PER : NT32;
    const short* hp = (const short*)hcatB + (r0 + l31)*CH + half*8;
    bf16x8 a0 = *(const bf16x8*)hp;
    bf16x8 a1 = *(const bf16x8*)(hp + 16);
    float acc[16];
    #pragma unroll
    for (int r = 0; r < 16; ++r) acc[r] = 0.f;
    for (int nt = n0; nt < n1; ++nt) {
        int v0 = nt*32;
        const short* bp = (const short*)WhoB + (long)(v0 + l31)*CH + half*8;
        bf16x8 b0 = *(const bf16x8*)bp;
        bf16x8 b1 = *(const bf16x8*)(bp + 16);
        float bv = bhoP[v0 + l31];
        f32x16 d;
        #pragma unroll
        for (int r = 0; r < 16; ++r) d[r] = bv;     // bias-seeded accumulator
        d = __builtin_amdgcn_mfma_f32_32x32x16_bf16(a0, b0, d, 0, 0, 0);
        d = __builtin_amdgcn_mfma_f32_32x32x16_bf16(a1, b1, d, 0, 0, 0);
        #pragma unroll
        for (int r = 0; r < 16; ++r) acc[r] += __expf(d[r]);
    }
    #pragma unroll
    for (int off = 1; off < 32; off <<= 1) {        // reduce over 32-lane half
        #pragma unroll
        for (int r = 0; r < 16; ++r) acc[r] += __shfl_xor(acc[r], off);
    }
    if (l31 == 0) {
        #pragma unroll
        for (int r = 0; r < 16; ++r)
            atomicAdd(&row_sums[r0 + (r&3) + 8*(r>>2) + 4*half], acc[r]);
    }
}

// ---- kB: recompute logits, seed accum with (bias - logZ), store ----------
// Store pattern: per reg, each 32-lane half writes 128B contiguous.
__global__ __launch_bounds__(256) void kB(
    const __hip_bfloat16* __restrict__ hcatB, const __hip_bfloat16* __restrict__ WhoB,
    const float* __restrict__ bhoP, const float* __restrict__ row_sums,
    float* __restrict__ out)
{
    int t = threadIdx.x, w = t >> 6, lane = t & 63;
    int l31 = lane & 31, half = lane >> 5;
    int r0 = (blockIdx.y*4 + w)*32;
    int n0 = blockIdx.x*NT_PER;
    int n1 = (n0 + NT_PER < NT32) ? n0 + NT_PER : NT32;
    const short* hp = (const short*)hcatB + (r0 + l31)*CH + half*8;
    bf16x8 a0 = *(const bf16x8*)hp;
    bf16x8 a1 = *(const bf16x8*)(hp + 16);
    float    lzr[16];
    unsigned obase[16];
    #pragma unroll
    for (int r = 0; r < 16; ++r) {
        int row = r0 + (r&3) + 8*(r>>2) + 4*half;
        lzr[r]   = logf(row_sums[row]);
        obase[r] = (unsigned)row*V + l31;           // max < 103M, fits u32
    }
    for (int nt = n0; nt < n1; ++nt) {
        int v0 = nt*32;
        const short* bp = (const short*)WhoB + (long)(v0 + l31)*CH + half*8;
        bf16x8 b0 = *(const bf16x8*)bp;
        bf16x8 b1 = *(const bf16x8*)(bp + 16);
        float bv = bhoP[v0 + l31];
        f32x16 d;
        #pragma unroll
        for (int r = 0; r < 16; ++r) d[r] = bv - lzr[r];   // seed epilogue
        d = __builtin_amdgcn_mfma_f32_32x32x16_bf16(a0, b0, d, 0, 0, 0);
        d = __builtin_amdgcn_mfma_f32_32x32x16_bf16(a1, b1, d, 0, 0, 0);
        if (v0 + l31 < V) {
            #pragma unroll
            for (int r = 0; r < 16; ++r) out[obase[r] + v0] = d[r];
        }
    }
}

extern "C" void kernel_launch(void* const* d_in, const int* in_sizes, int n_in,
                              void* d_out, int out_size, void* d_ws, size_t ws_size,
                              hipStream_t stream)
{
    const int*   tok = (const int*)d_in[0];
    const float* emb = (const float*)d_in[1];
    const float* Wf  = (const float*)d_in[2];
    const float* bf  = (const float*)d_in[3];
    const float* Wi  = (const float*)d_in[4];
    const float* bi  = (const float*)d_in[5];
    const float* Wc  = (const float*)d_in[6];
    const float* bc  = (const float*)d_in[7];
    const float* Wo  = (const float*)d_in[8];
    const float* bo  = (const float*)d_in[9];
    const float* Who = (const float*)d_in[10];
    const float* bho = (const float*)d_in[11];
    const float* h0  = (const float*)d_in[12];
    const float* C0  = (const float*)d_in[13];
    float* out = (float*)d_out;

    char* p = (char*)d_ws;
    __hip_bfloat16* WhoB  = (__hip_bfloat16*)p; p += (size_t)VPAD*CH*2;  // 3.2 MB
    __hip_bfloat16* hcatB = (__hip_bfloat16*)p; p += (size_t)S*B*CH*2;   // 128 KB
    float* bhoP     = (float*)p; p += (size_t)VPAD*4;
    float* xw       = (float*)p; p += (size_t)S*B*64*4;
    float* row_sums = (float*)p;

    kprep<<<dim3(NB_CONV + NB_XW), dim3(256), 0, stream>>>(
        tok, emb, Wf, bf, Wi, bi, Wc, bc, Wo, bo, Who, bho,
        WhoB, bhoP, xw, row_sums);
    k2_scan<<<dim3(64), dim3(64), 0, stream>>>(xw, Wf, Wi, Wc, Wo, h0, C0, hcatB);
    dim3 g(NSTRIP, MT32/4);   // (32, 16) = 512 blocks
    kA<<<g, dim3(256), 0, stream>>>(hcatB, WhoB, bhoP, row_sums);
    kB<<<g, dim3(256), 0, stream>>>(hcatB, WhoB, bhoP, row_sums, out);
}